// Round 1
// baseline (1998.715 us; speedup 1.0000x reference)
//
#include <hip/hip_runtime.h>

#define IN_DIM 128
#define HID 64

// ---------------- Kernel 1: h1 = x @ W1 + b1   [N,128]@[128,64] ----------------
// Block = 256 threads. W1 (32 KB) staged in LDS. Thread (jg, rsub) computes
// 4 consecutive output cols (j0=4*jg) for 2 rows (rsub, rsub+16) => 32 rows/block.
__global__ __launch_bounds__(256) void gemm1_kernel(
    const float* __restrict__ x, const float* __restrict__ W1,
    const float* __restrict__ b1, float* __restrict__ h1, int N) {
  __shared__ float Ws[IN_DIM][HID];
  for (int i = threadIdx.x; i < IN_DIM * HID / 4; i += 256)
    reinterpret_cast<float4*>(&Ws[0][0])[i] = reinterpret_cast<const float4*>(W1)[i];
  __syncthreads();

  const int jg   = threadIdx.x & 15;
  const int j0   = jg * 4;
  const int rsub = threadIdx.x >> 4;
  const int r0 = blockIdx.x * 32 + rsub;
  const int r1 = r0 + 16;
  const bool v0 = r0 < N, v1 = r1 < N;

  float a0[4] = {0.f, 0.f, 0.f, 0.f};
  float a1[4] = {0.f, 0.f, 0.f, 0.f};

  const float4* xr0 = reinterpret_cast<const float4*>(x + (long)r0 * IN_DIM);
  const float4* xr1 = reinterpret_cast<const float4*>(x + (long)r1 * IN_DIM);

  for (int k4 = 0; k4 < IN_DIM / 4; ++k4) {
    float4 xv0 = v0 ? xr0[k4] : make_float4(0.f, 0.f, 0.f, 0.f);
    float4 xv1 = v1 ? xr1[k4] : make_float4(0.f, 0.f, 0.f, 0.f);
    float xs0[4], xs1[4];
    *reinterpret_cast<float4*>(xs0) = xv0;
    *reinterpret_cast<float4*>(xs1) = xv1;
#pragma unroll
    for (int kk = 0; kk < 4; ++kk) {
      float4 wv = *reinterpret_cast<const float4*>(&Ws[k4 * 4 + kk][j0]);
      float wvs[4];
      *reinterpret_cast<float4*>(wvs) = wv;
#pragma unroll
      for (int c = 0; c < 4; ++c) {
        a0[c] += xs0[kk] * wvs[c];
        a1[c] += xs1[kk] * wvs[c];
      }
    }
  }

  float bb[4];
  *reinterpret_cast<float4*>(bb) = *reinterpret_cast<const float4*>(&b1[j0]);
  if (v0) {
    float4 o = make_float4(a0[0] + bb[0], a0[1] + bb[1], a0[2] + bb[2], a0[3] + bb[3]);
    *reinterpret_cast<float4*>(h1 + (long)r0 * HID + j0) = o;
  }
  if (v1) {
    float4 o = make_float4(a1[0] + bb[0], a1[1] + bb[1], a1[2] + bb[2], a1[3] + bb[3]);
    *reinterpret_cast<float4*>(h1 + (long)r1 * HID + j0) = o;
  }
}

// ---------------- Kernel 2: h2[dst] += w * h1[src]  (64-dim scatter) ----------------
// Thread handles one edge x 4 dims (float4 gather + 4 atomicAdds). 16 threads/edge.
__global__ __launch_bounds__(256) void spmm1_kernel(
    const int* __restrict__ src, const int* __restrict__ dst,
    const float* __restrict__ w, const float* __restrict__ hin,
    float* __restrict__ hout, int E) {
  long tid = (long)blockIdx.x * 256 + threadIdx.x;
  if (tid >= (long)E * 16) return;
  int e  = (int)(tid >> 4);
  int j0 = ((int)tid & 15) * 4;
  int s = src[e], d = dst[e];
  float ww = w[e];
  float4 v = *reinterpret_cast<const float4*>(hin + (long)s * HID + j0);
  float* p = hout + (long)d * HID + j0;
  atomicAdd(p + 0, ww * v.x);
  atomicAdd(p + 1, ww * v.y);
  atomicAdd(p + 2, ww * v.z);
  atomicAdd(p + 3, ww * v.w);
}

// ---------------- Kernel 3: h3 = relu(h2) @ W2 + b2  (dot-64 per node) ----------------
__global__ __launch_bounds__(256) void lin2_kernel(
    const float* __restrict__ h2, const float* __restrict__ W2,
    const float* __restrict__ b2, float* __restrict__ h3, int N) {
  __shared__ float W2s[HID];
  if (threadIdx.x < HID) W2s[threadIdx.x] = W2[threadIdx.x];
  __syncthreads();
  int n = blockIdx.x * 256 + threadIdx.x;
  if (n >= N) return;
  const float4* hp = reinterpret_cast<const float4*>(h2 + (long)n * HID);
  float acc = 0.f;
#pragma unroll
  for (int j4 = 0; j4 < HID / 4; ++j4) {
    float4 v = hp[j4];
    float vs[4];
    *reinterpret_cast<float4*>(vs) = v;
#pragma unroll
    for (int c = 0; c < 4; ++c) {
      float r = vs[c] > 0.f ? vs[c] : 0.f;
      acc += r * W2s[j4 * 4 + c];
    }
  }
  h3[n] = acc + b2[0];
}

// ---------------- Kernel 4: out[dst] += w * h3[src]  (scalar scatter) ----------------
__global__ __launch_bounds__(256) void spmm2_kernel(
    const int* __restrict__ src, const int* __restrict__ dst,
    const float* __restrict__ w, const float* __restrict__ h3,
    float* __restrict__ out, int E) {
  int e = blockIdx.x * 256 + threadIdx.x;
  if (e >= E) return;
  atomicAdd(&out[dst[e]], w[e] * h3[src[e]]);
}

extern "C" void kernel_launch(void* const* d_in, const int* in_sizes, int n_in,
                              void* d_out, int out_size, void* d_ws, size_t ws_size,
                              hipStream_t stream) {
  const float* x    = (const float*)d_in[0];
  const int*   esrc = (const int*)d_in[1];
  const int*   edst = (const int*)d_in[2];
  const float* ew   = (const float*)d_in[3];
  const float* W1   = (const float*)d_in[4];
  const float* b1   = (const float*)d_in[5];
  const float* W2   = (const float*)d_in[6];
  const float* b2   = (const float*)d_in[7];
  float* out = (float*)d_out;

  const int N = in_sizes[0] / IN_DIM;
  const int E = in_sizes[1];

  char* ws = (char*)d_ws;
  float* h1 = (float*)ws;                                        // N*64 f32 = 25.6 MB
  float* h2 = (float*)(ws + (size_t)N * HID * sizeof(float));    // N*64 f32 = 25.6 MB
  float* h3 = (float*)(ws + 2 * (size_t)N * HID * sizeof(float)); // N f32 = 0.4 MB

  // Zero accumulators (d_out/d_ws are poisoned, not re-zeroed between replays).
  hipMemsetAsync(h2, 0, (size_t)N * HID * sizeof(float), stream);
  hipMemsetAsync(out, 0, (size_t)N * sizeof(float), stream);

  gemm1_kernel<<<(N + 31) / 32, 256, 0, stream>>>(x, W1, b1, h1, N);

  long t1 = (long)E * 16;
  spmm1_kernel<<<(unsigned)((t1 + 255) / 256), 256, 0, stream>>>(esrc, edst, ew, h1, h2, E);

  lin2_kernel<<<(N + 255) / 256, 256, 0, stream>>>(h2, W2, b2, h3, N);

  spmm2_kernel<<<(E + 255) / 256, 256, 0, stream>>>(esrc, edst, ew, h3, out, E);
}

// Round 2
// 861.119 us; speedup vs baseline: 2.3211x; 2.3211x over previous
//
#include <hip/hip_runtime.h>

#define IN_DIM 128
#define HID 64

// ---------------- Kernel 1: h1 = x @ W1 + b1   [N,128]@[128,64] ----------------
__global__ __launch_bounds__(256) void gemm1_kernel(
    const float* __restrict__ x, const float* __restrict__ W1,
    const float* __restrict__ b1, float* __restrict__ h1, int N) {
  __shared__ float Ws[IN_DIM][HID];
  for (int i = threadIdx.x; i < IN_DIM * HID / 4; i += 256)
    reinterpret_cast<float4*>(&Ws[0][0])[i] = reinterpret_cast<const float4*>(W1)[i];
  __syncthreads();

  const int jg   = threadIdx.x & 15;
  const int j0   = jg * 4;
  const int rsub = threadIdx.x >> 4;
  const int r0 = blockIdx.x * 32 + rsub;
  const int r1 = r0 + 16;
  const bool v0 = r0 < N, v1 = r1 < N;

  float a0[4] = {0.f, 0.f, 0.f, 0.f};
  float a1[4] = {0.f, 0.f, 0.f, 0.f};

  const float4* xr0 = reinterpret_cast<const float4*>(x + (long)r0 * IN_DIM);
  const float4* xr1 = reinterpret_cast<const float4*>(x + (long)r1 * IN_DIM);

  for (int k4 = 0; k4 < IN_DIM / 4; ++k4) {
    float4 xv0 = v0 ? xr0[k4] : make_float4(0.f, 0.f, 0.f, 0.f);
    float4 xv1 = v1 ? xr1[k4] : make_float4(0.f, 0.f, 0.f, 0.f);
    float xs0[4], xs1[4];
    *reinterpret_cast<float4*>(xs0) = xv0;
    *reinterpret_cast<float4*>(xs1) = xv1;
#pragma unroll
    for (int kk = 0; kk < 4; ++kk) {
      float4 wv = *reinterpret_cast<const float4*>(&Ws[k4 * 4 + kk][j0]);
      float wvs[4];
      *reinterpret_cast<float4*>(wvs) = wv;
#pragma unroll
      for (int c = 0; c < 4; ++c) {
        a0[c] += xs0[kk] * wvs[c];
        a1[c] += xs1[kk] * wvs[c];
      }
    }
  }

  float bb[4];
  *reinterpret_cast<float4*>(bb) = *reinterpret_cast<const float4*>(&b1[j0]);
  if (v0) {
    float4 o = make_float4(a0[0] + bb[0], a0[1] + bb[1], a0[2] + bb[2], a0[3] + bb[3]);
    *reinterpret_cast<float4*>(h1 + (long)r0 * HID + j0) = o;
  }
  if (v1) {
    float4 o = make_float4(a1[0] + bb[0], a1[1] + bb[1], a1[2] + bb[2], a1[3] + bb[3]);
    *reinterpret_cast<float4*>(h1 + (long)r1 * HID + j0) = o;
  }
}

// ---------------- CSR build: histogram -> scan -> scatter ----------------
__global__ __launch_bounds__(256) void hist_kernel(
    const int* __restrict__ dst, int* __restrict__ counts, int E) {
  int e = blockIdx.x * 256 + threadIdx.x;
  if (e < E) atomicAdd(&counts[dst[e]], 1);
}

// Per-block exclusive scan of counts -> offs (block-local), block total -> partials.
__global__ __launch_bounds__(256) void scan1_kernel(
    const int* __restrict__ counts, int* __restrict__ offs,
    int* __restrict__ partials, int N) {
  __shared__ int tmp[256];
  int i = blockIdx.x * 256 + threadIdx.x;
  int v = (i < N) ? counts[i] : 0;
  tmp[threadIdx.x] = v;
  __syncthreads();
  for (int off = 1; off < 256; off <<= 1) {
    int t = (threadIdx.x >= off) ? tmp[threadIdx.x - off] : 0;
    __syncthreads();
    tmp[threadIdx.x] += t;
    __syncthreads();
  }
  if (i < N) offs[i] = tmp[threadIdx.x] - v;  // block-local exclusive
  if (threadIdx.x == 255) partials[blockIdx.x] = tmp[255];
}

// Single-block exclusive scan of partials (nb <= 1024).
__global__ __launch_bounds__(1024) void scan2_kernel(int* __restrict__ partials, int nb) {
  __shared__ int tmp[1024];
  int tid = threadIdx.x;
  int v = (tid < nb) ? partials[tid] : 0;
  tmp[tid] = v;
  __syncthreads();
  for (int off = 1; off < 1024; off <<= 1) {
    int t = (tid >= off) ? tmp[tid - off] : 0;
    __syncthreads();
    tmp[tid] += t;
    __syncthreads();
  }
  if (tid < nb) partials[tid] = tmp[tid] - v;  // exclusive
}

// Add back block bases; init cursor; set offs[N] = E.
__global__ __launch_bounds__(256) void scan3_kernel(
    int* __restrict__ offs, const int* __restrict__ partials,
    const int* __restrict__ counts, int* __restrict__ cursor, int N) {
  int i = blockIdx.x * 256 + threadIdx.x;
  if (i >= N) return;
  int o = offs[i] + partials[blockIdx.x];
  offs[i] = o;
  cursor[i] = o;
  if (i == N - 1) offs[N] = o + counts[i];
}

__global__ __launch_bounds__(256) void scatter_kernel(
    const int* __restrict__ src, const int* __restrict__ dst,
    const float* __restrict__ w, int* __restrict__ cursor,
    int* __restrict__ csr_src, float* __restrict__ csr_w, int E) {
  int e = blockIdx.x * 256 + threadIdx.x;
  if (e >= E) return;
  int d = dst[e];
  int pos = atomicAdd(&cursor[d], 1);
  csr_src[pos] = src[e];
  csr_w[pos]  = w[e];
}

// ---------------- Fused: h3[n] = relu(sum_e w*h1[src_e]) . W2 + b2 ----------------
// One 64-lane wave per node; lane = hidden dim.
__global__ __launch_bounds__(256) void spmm1_fused_kernel(
    const int* __restrict__ offs, const int* __restrict__ csr_src,
    const float* __restrict__ csr_w, const float* __restrict__ h1,
    const float* __restrict__ W2, const float* __restrict__ b2,
    float* __restrict__ h3, int N) {
  int wave = (blockIdx.x * 256 + threadIdx.x) >> 6;
  int lane = threadIdx.x & 63;
  if (wave >= N) return;
  int beg = offs[wave], end = offs[wave + 1];
  float acc = 0.f;
  int k = beg;
  // unroll-2 for ILP
  for (; k + 1 < end; k += 2) {
    int   s0 = csr_src[k],   s1 = csr_src[k + 1];
    float w0 = csr_w[k],     w1 = csr_w[k + 1];
    float v0 = h1[(long)s0 * HID + lane];
    float v1 = h1[(long)s1 * HID + lane];
    acc += w0 * v0;
    acc += w1 * v1;
  }
  if (k < end) {
    acc += csr_w[k] * h1[(long)csr_src[k] * HID + lane];
  }
  float r = fmaxf(acc, 0.f) * W2[lane];
#pragma unroll
  for (int off = 32; off > 0; off >>= 1) r += __shfl_down(r, off, 64);
  if (lane == 0) h3[wave] = r + b2[0];
}

// ---------------- Gather spmm2: out[n] = sum_e w*h3[src_e] ----------------
__global__ __launch_bounds__(256) void spmm2_gather_kernel(
    const int* __restrict__ offs, const int* __restrict__ csr_src,
    const float* __restrict__ csr_w, const float* __restrict__ h3,
    float* __restrict__ out, int N) {
  int n = blockIdx.x * 256 + threadIdx.x;
  if (n >= N) return;
  int beg = offs[n], end = offs[n + 1];
  float acc = 0.f;
  for (int k = beg; k < end; ++k)
    acc += csr_w[k] * h3[csr_src[k]];
  out[n] = acc;
}

extern "C" void kernel_launch(void* const* d_in, const int* in_sizes, int n_in,
                              void* d_out, int out_size, void* d_ws, size_t ws_size,
                              hipStream_t stream) {
  const float* x    = (const float*)d_in[0];
  const int*   esrc = (const int*)d_in[1];
  const int*   edst = (const int*)d_in[2];
  const float* ew   = (const float*)d_in[3];
  const float* W1   = (const float*)d_in[4];
  const float* b1   = (const float*)d_in[5];
  const float* W2   = (const float*)d_in[6];
  const float* b2   = (const float*)d_in[7];
  float* out = (float*)d_out;

  const int N = in_sizes[0] / IN_DIM;
  const int E = in_sizes[1];

  // Workspace layout (all 16B-aligned enough; base is aligned)
  float* h1      = (float*)d_ws;                   // N*HID floats
  float* h3      = h1 + (size_t)N * HID;           // N floats
  int*   counts  = (int*)(h3 + N);                 // N ints
  int*   offs    = counts + N;                     // N+1 ints
  int*   cursor  = offs + N + 1;                   // N ints
  int*   partials= cursor + N;                     // 1024 ints
  int*   csr_src = partials + 1024;                // E ints
  float* csr_w   = (float*)(csr_src + E);          // E floats

  const int nbN = (N + 255) / 256;   // blocks over nodes
  const int nbE = (E + 255) / 256;   // blocks over edges

  // counts must start at zero every call (ws is NOT re-zeroed between replays)
  hipMemsetAsync(counts, 0, (size_t)N * sizeof(int), stream);

  gemm1_kernel<<<(N + 31) / 32, 256, 0, stream>>>(x, W1, b1, h1, N);

  hist_kernel<<<nbE, 256, 0, stream>>>(edst, counts, E);
  scan1_kernel<<<nbN, 256, 0, stream>>>(counts, offs, partials, N);
  scan2_kernel<<<1, 1024, 0, stream>>>(partials, nbN);
  scan3_kernel<<<nbN, 256, 0, stream>>>(offs, partials, counts, cursor, N);
  scatter_kernel<<<nbE, 256, 0, stream>>>(esrc, edst, ew, cursor, csr_src, csr_w, E);

  // Fused spmm1 + relu + lin2: one wave per node
  {
    long waves = N;
    long blocks = (waves * 64 + 255) / 256;
    spmm1_fused_kernel<<<(unsigned)blocks, 256, 0, stream>>>(
        offs, csr_src, csr_w, h1, W2, b2, h3, N);
  }

  spmm2_gather_kernel<<<nbN, 256, 0, stream>>>(offs, csr_src, csr_w, h3, out, N);
}

// Round 3
// 354.478 us; speedup vs baseline: 5.6385x; 2.4293x over previous
//
#include <hip/hip_runtime.h>

#define IN_DIM 128
#define HID 64

// ---------------- Kernel 1: h1 = x @ W1 + b1   [N,128]@[128,64] ----------------
// Block = 256 threads -> 64x64 output tile. Thread (ty,tx) computes rows
// rbase+4ty..+3, cols 4tx..4tx+3 (4x4 micro-tile, 16 acc). W1 in LDS.
// #pragma unroll 1 on k-loop: prevents unroll-and-hoist VGPR blowup (R2: 256
// VGPR + 900 MB spill traffic each way).
__global__ __launch_bounds__(256) void gemm1_kernel(
    const float* __restrict__ x, const float* __restrict__ W1,
    const float* __restrict__ b1, float* __restrict__ h1, int N) {
  __shared__ float Ws[IN_DIM][HID];
  for (int i = threadIdx.x; i < IN_DIM * HID / 4; i += 256)
    reinterpret_cast<float4*>(&Ws[0][0])[i] = reinterpret_cast<const float4*>(W1)[i];
  __syncthreads();

  const int tx = threadIdx.x & 15;   // col quad
  const int ty = threadIdx.x >> 4;   // row group
  const int j0 = tx * 4;
  const int rbase = blockIdx.x * 64 + ty * 4;

  float acc[4][4];
#pragma unroll
  for (int i = 0; i < 4; ++i)
#pragma unroll
    for (int c = 0; c < 4; ++c) acc[i][c] = 0.f;

  const float4* xp[4];
#pragma unroll
  for (int i = 0; i < 4; ++i) {
    int r = rbase + i;
    if (r > N - 1) r = N - 1;  // clamp loads; stores guarded below
    xp[i] = reinterpret_cast<const float4*>(x + (long)r * IN_DIM);
  }

#pragma unroll 1
  for (int k4 = 0; k4 < IN_DIM / 4; ++k4) {
    float xs[4][4];
#pragma unroll
    for (int i = 0; i < 4; ++i)
      *reinterpret_cast<float4*>(xs[i]) = xp[i][k4];
#pragma unroll
    for (int kk = 0; kk < 4; ++kk) {
      float wv[4];
      *reinterpret_cast<float4*>(wv) =
          *reinterpret_cast<const float4*>(&Ws[k4 * 4 + kk][j0]);
#pragma unroll
      for (int i = 0; i < 4; ++i)
#pragma unroll
        for (int c = 0; c < 4; ++c)
          acc[i][c] += xs[i][kk] * wv[c];
    }
  }

  float bb[4];
  *reinterpret_cast<float4*>(bb) = *reinterpret_cast<const float4*>(&b1[j0]);
#pragma unroll
  for (int i = 0; i < 4; ++i) {
    int r = rbase + i;
    if (r < N) {
      float4 o = make_float4(acc[i][0] + bb[0], acc[i][1] + bb[1],
                             acc[i][2] + bb[2], acc[i][3] + bb[3]);
      *reinterpret_cast<float4*>(h1 + (long)r * HID + j0) = o;
    }
  }
}

// ---------------- CSR build: histogram -> scan -> scatter ----------------
__global__ __launch_bounds__(256) void hist_kernel(
    const int* __restrict__ dst, int* __restrict__ counts, int E) {
  int e = blockIdx.x * 256 + threadIdx.x;
  if (e < E) atomicAdd(&counts[dst[e]], 1);
}

__global__ __launch_bounds__(256) void scan1_kernel(
    const int* __restrict__ counts, int* __restrict__ offs,
    int* __restrict__ partials, int N) {
  __shared__ int tmp[256];
  int i = blockIdx.x * 256 + threadIdx.x;
  int v = (i < N) ? counts[i] : 0;
  tmp[threadIdx.x] = v;
  __syncthreads();
  for (int off = 1; off < 256; off <<= 1) {
    int t = (threadIdx.x >= off) ? tmp[threadIdx.x - off] : 0;
    __syncthreads();
    tmp[threadIdx.x] += t;
    __syncthreads();
  }
  if (i < N) offs[i] = tmp[threadIdx.x] - v;  // block-local exclusive
  if (threadIdx.x == 255) partials[blockIdx.x] = tmp[255];
}

__global__ __launch_bounds__(1024) void scan2_kernel(int* __restrict__ partials, int nb) {
  __shared__ int tmp[1024];
  int tid = threadIdx.x;
  int v = (tid < nb) ? partials[tid] : 0;
  tmp[tid] = v;
  __syncthreads();
  for (int off = 1; off < 1024; off <<= 1) {
    int t = (tid >= off) ? tmp[tid - off] : 0;
    __syncthreads();
    tmp[tid] += t;
    __syncthreads();
  }
  if (tid < nb) partials[tid] = tmp[tid] - v;  // exclusive
}

__global__ __launch_bounds__(256) void scan3_kernel(
    int* __restrict__ offs, const int* __restrict__ partials,
    const int* __restrict__ counts, int* __restrict__ cursor, int N) {
  int i = blockIdx.x * 256 + threadIdx.x;
  if (i >= N) return;
  int o = offs[i] + partials[blockIdx.x];
  offs[i] = o;
  cursor[i] = o;
  if (i == N - 1) offs[N] = o + counts[i];
}

// Pack (src, weight-bits) into one int2 -> single 8 B random write per edge.
__global__ __launch_bounds__(256) void scatter_kernel(
    const int* __restrict__ src, const int* __restrict__ dst,
    const float* __restrict__ w, int* __restrict__ cursor,
    int2* __restrict__ csr, int E) {
  int e = blockIdx.x * 256 + threadIdx.x;
  if (e >= E) return;
  int d = dst[e];
  int pos = atomicAdd(&cursor[d], 1);
  csr[pos] = make_int2(src[e], __float_as_int(w[e]));
}

// ---------------- Fused: h3[n] = relu(sum_e w*h1[src_e]) . W2 + b2 ----------------
// One 64-lane wave per node; lane = hidden dim.
__global__ __launch_bounds__(256) void spmm1_fused_kernel(
    const int* __restrict__ offs, const int2* __restrict__ csr,
    const float* __restrict__ h1, const float* __restrict__ W2,
    const float* __restrict__ b2, float* __restrict__ h3, int N) {
  int wave = (blockIdx.x * 256 + threadIdx.x) >> 6;
  int lane = threadIdx.x & 63;
  if (wave >= N) return;
  int beg = offs[wave], end = offs[wave + 1];
  float acc = 0.f;
  int k = beg;
  for (; k + 1 < end; k += 2) {
    int2 e0 = csr[k], e1 = csr[k + 1];
    float v0 = h1[(long)e0.x * HID + lane];
    float v1 = h1[(long)e1.x * HID + lane];
    acc += __int_as_float(e0.y) * v0;
    acc += __int_as_float(e1.y) * v1;
  }
  if (k < end) {
    int2 e = csr[k];
    acc += __int_as_float(e.y) * h1[(long)e.x * HID + lane];
  }
  float r = fmaxf(acc, 0.f) * W2[lane];
#pragma unroll
  for (int off = 32; off > 0; off >>= 1) r += __shfl_down(r, off, 64);
  if (lane == 0) h3[wave] = r + b2[0];
}

// ---------------- Gather spmm2: out[n] = sum_e w*h3[src_e] ----------------
__global__ __launch_bounds__(256) void spmm2_gather_kernel(
    const int* __restrict__ offs, const int2* __restrict__ csr,
    const float* __restrict__ h3, float* __restrict__ out, int N) {
  int n = blockIdx.x * 256 + threadIdx.x;
  if (n >= N) return;
  int beg = offs[n], end = offs[n + 1];
  float acc = 0.f;
  for (int k = beg; k < end; ++k) {
    int2 e = csr[k];
    acc += __int_as_float(e.y) * h3[e.x];
  }
  out[n] = acc;
}

extern "C" void kernel_launch(void* const* d_in, const int* in_sizes, int n_in,
                              void* d_out, int out_size, void* d_ws, size_t ws_size,
                              hipStream_t stream) {
  const float* x    = (const float*)d_in[0];
  const int*   esrc = (const int*)d_in[1];
  const int*   edst = (const int*)d_in[2];
  const float* ew   = (const float*)d_in[3];
  const float* W1   = (const float*)d_in[4];
  const float* b1   = (const float*)d_in[5];
  const float* W2   = (const float*)d_in[6];
  const float* b2   = (const float*)d_in[7];
  float* out = (float*)d_out;

  const int N = in_sizes[0] / IN_DIM;
  const int E = in_sizes[1];

  // Workspace layout (offsets kept 8B-aligned; offs padded to N+2)
  float* h1      = (float*)d_ws;                   // N*HID floats
  float* h3      = h1 + (size_t)N * HID;           // N floats
  int*   counts  = (int*)(h3 + N);                 // N ints
  int*   offs    = counts + N;                     // N+2 ints (pad for alignment)
  int*   cursor  = offs + N + 2;                   // N ints
  int*   partials= cursor + N;                     // 1024 ints
  int2*  csr     = (int2*)(partials + 1024);       // E int2 (src, w-bits)

  const int nbN = (N + 255) / 256;
  const int nbE = (E + 255) / 256;

  hipMemsetAsync(counts, 0, (size_t)N * sizeof(int), stream);

  gemm1_kernel<<<(N + 63) / 64, 256, 0, stream>>>(x, W1, b1, h1, N);

  hist_kernel<<<nbE, 256, 0, stream>>>(edst, counts, E);
  scan1_kernel<<<nbN, 256, 0, stream>>>(counts, offs, partials, N);
  scan2_kernel<<<1, 1024, 0, stream>>>(partials, nbN);
  scan3_kernel<<<nbN, 256, 0, stream>>>(offs, partials, counts, cursor, N);
  scatter_kernel<<<nbE, 256, 0, stream>>>(esrc, edst, ew, cursor, csr, E);

  spmm1_fused_kernel<<<(unsigned)(((long)N * 64 + 255) / 256), 256, 0, stream>>>(
      offs, csr, h1, W2, b2, h3, N);

  spmm2_gather_kernel<<<nbN, 256, 0, stream>>>(offs, csr, h3, out, N);
}